// Round 3
// baseline (162.540 us; speedup 1.0000x reference)
//
#include <hip/hip_runtime.h>

// CRF loss on MI355X — R3: SGPR-resident state vector.
// B=512, L=512, T=32, S=34. Output f32[512].
//
// Linear-domain forward algorithm. Per block (128 thr): wave0 = forward chain,
// wave1 = backward chain (meet at t=256). State alpha[0..31] lives in 32 SGPRs
// (wave-uniform); lane c holds the T-column tc[p] in VGPRs and computes
// alpha'[c] = sum_p s_alpha[p] * v_tc[p]  -> 32 v_fmac with SGPR operand.
// State returns to SGPRs via 32 v_readlane. No LDS / barriers / shuffles on
// the recurrence chain. Rescale: exact power-of-2 via exponent of su[0]
// (SALU) applied with one v_ldexp_f32 — bitwise-equivalent linear math.
// Lanes 32-63 duplicate lanes 0-31 (readlane sources lanes 0-31).

#define F2  1.4426950408889634f   // log2(e)
#define LN2 0.6931471805599453f

__device__ __forceinline__ float rdlane(float v, int p) {
    return __int_as_float(__builtin_amdgcn_readlane(__float_as_int(v), p));
}

__global__ __launch_bounds__(128) void crf_kernel(
    const float* __restrict__ wtv,    // [512,512,32]
    const float* __restrict__ trans,  // [34,34]
    const int*   __restrict__ rtag,   // [512,512]
    float* __restrict__ out)          // [512]
{
    __shared__ __align__(16) float tlds[1156];
    __shared__ float xv[64];   // epilogue: [0..31] af_256, [32..63] beta_256
    __shared__ float xs[2];    // epilogue: path sums (fwd, bwd)
    __shared__ int   xe[2];    // epilogue: scale exponents

    const int  b   = blockIdx.x;
    const int  tid = threadIdx.x;
    const int  h   = tid >> 6;           // 0 = fwd wave, 1 = bwd wave
    const bool isB = (h != 0);
    const int  l   = tid & 63;
    const int  c   = l & 31;             // state-1 (states 1..32)

    for (int k = tid; k < 1156; k += 128) tlds[k] = trans[k];
    __syncthreads();

    // T-operand per lane: fwd: tc[p] = expT[p+1][c+1]; bwd: tc[p] = expT[c+1][p+1]
    float tc[32];
    #pragma unroll
    for (int p = 0; p < 32; ++p) {
        float tv = isB ? tlds[(c + 1) * 34 + (p + 1)]
                       : tlds[(p + 1) * 34 + (c + 1)];
        tc[p] = __builtin_exp2f(F2 * tv);
    }
    // START contribution (fwd only), added at i==1: + expT[0][c+1]
    float accInitV = isB ? 0.0f : __builtin_exp2f(F2 * tlds[c + 1]);

    const float* wb = wtv + (size_t)b * (512 * 32);
    const int*   tb = rtag + (size_t)b * 512;

    // iteration i (1..256) uses emission row: fwd i, bwd 511-i
    const int rowstride = isB ? -32 : 32;

    // init published vector: fwd alpha_0 = eo(row0); bwd g_511 = eo(row511)
    float v0   = wb[(isB ? 511 * 32 : 0) + c];
    float pub0 = __builtin_exp2f(F2 * v0);
    float su[32];
    #pragma unroll
    for (int p = 0; p < 32; ++p) su[p] = rdlane(pub0, p);

    int scaleE = 0;
    int kCur   = ((__float_as_int(su[0]) >> 23) & 0xff) - 127;

    // gold-path state
    int  tb0   = tb[0];
    int  pt    = isB ? 33 : tb0;                         // bwd sentinel -> end term first
    float pathT = isB ? 0.0f : tlds[tb0];                // start term trans[0][tag_0]
    float pathE = (!isB && (c == tb0 - 1)) ? v0 : 0.0f;  // row-0 gold emission (fwd)
    float pv    = v0;                                    // bwd lagged emission (row 512-i)

    // tag prefetch (uniform -> SGPRs): ctg[j] = tag for iteration i=t0+j
    int ctg[8], ntg[8];
    #pragma unroll
    for (int j = 0; j < 8; ++j) ctg[j] = tb[isB ? (511 - j) : (1 + j)];

    // emission prefetch, one 8-block ahead
    float vn[8], vc[8], eo[8];
    {
        const float* p0 = wb + (isB ? 510 * 32 : 32) + c;  // rows for i=1..8
        #pragma unroll
        for (int j = 0; j < 8; ++j) vn[j] = p0[j * rowstride];
    }

    float res = pub0, bKeep = 0.0f;
    int   bScale = 0;

    for (int t0 = 1; t0 <= 249; t0 += 8) {   // 32 blocks, i = t0..t0+7
        const bool last = (t0 == 249);
        #pragma unroll
        for (int j = 0; j < 8; ++j) { vc[j] = vn[j]; eo[j] = __builtin_exp2f(F2 * vc[j]); }
        {   // prefetch emissions for next block (rows always in-bounds)
            int row8 = isB ? (511 - (t0 + 8)) : (t0 + 8);
            const float* p0 = wb + row8 * 32 + c;
            #pragma unroll
            for (int j = 0; j < 8; ++j) vn[j] = p0[j * rowstride];
        }
        {   // prefetch tags for next block
            #pragma unroll
            for (int j = 0; j < 8; ++j) ntg[j] = tb[isB ? (504 - t0 - j) : (t0 + 8 + j)];
        }
        // batched gold-transition lookups for this block (consumed at block end)
        float ptv[8];
        #pragma unroll
        for (int j = 0; j < 8; ++j) {
            int ct  = ctg[j];
            int idx = isB ? (ct * 34 + pt) : (pt * 34 + ct);
            ptv[j]  = tlds[idx];
            pt      = ct;
        }
        float seedv = (t0 == 1) ? accInitV : 0.0f;

        #pragma unroll
        for (int j = 0; j < 8; ++j) {
            // matvec: lane c computes sum_p su[p] * tc[p]  (su uniform/SGPR)
            float a0 = 0.0f, a1 = 0.0f, a2 = 0.0f, a3 = 0.0f;
            #pragma unroll
            for (int p = 0; p < 32; p += 4) {
                a0 = fmaf(su[p + 0], tc[p + 0], a0);
                a1 = fmaf(su[p + 1], tc[p + 1], a1);
                a2 = fmaf(su[p + 2], tc[p + 2], a2);
                a3 = fmaf(su[p + 3], tc[p + 3], a3);
            }
            float s = (a0 + a1) + (a2 + a3);
            if (j == 0) s += seedv;

            float sS = ldexpf(s, -kCur);     // exact power-of-2 rescale
            scaleE += kCur;
            if (j == 6) {                     // bwd: capture beta_256 (i==255), pre-eo
                if (last && isB) { bKeep = sS; bScale = scaleE; }
            }
            res = sS * eo[j];

            // gold-path score (skip bwd's fwd-only tail step i==256)
            if (!(j == 7 && last && isB)) {
                int   ct = ctg[j];
                float em = isB ? pv : vc[j];
                pathE += (c == ct - 1) ? em : 0.0f;
            }
            pv = vc[j];

            // state -> SGPRs (skip on bwd's dead tail step)
            if (!(j == 7 && last && isB)) {
                #pragma unroll
                for (int p = 0; p < 32; ++p) su[p] = rdlane(res, p);
                kCur = ((__float_as_int(su[0]) >> 23) & 0xff) - 127;
            }
        }
        pathT += ((ptv[0] + ptv[1]) + (ptv[2] + ptv[3]))
               + ((ptv[4] + ptv[5]) + (ptv[6] + ptv[7]));
        #pragma unroll
        for (int j = 0; j < 8; ++j) ctg[j] = ntg[j];
    }

    // ---- epilogue ----
    float fin  = isB ? bKeep  : res;       // beta_256 / alpha_256 (lane c)
    int   finS = isB ? bScale : scaleE;

    float pe = pathE;                      // reduce over 32 states (halves duplicate)
    pe += __shfl_xor(pe, 1);
    pe += __shfl_xor(pe, 2);
    pe += __shfl_xor(pe, 4);
    pe += __shfl_xor(pe, 8);
    pe += __shfl_xor(pe, 16);

    if (l < 32) xv[h * 32 + c] = fin;
    if (l == 0) { xs[h] = pe + pathT; xe[h] = finS; }
    __syncthreads();

    if (h == 0) {
        float pr = xv[c] * xv[32 + c];     // af_256[c] * beta_256[c]
        pr += __shfl_xor(pr, 1);
        pr += __shfl_xor(pr, 2);
        pr += __shfl_xor(pr, 4);
        pr += __shfl_xor(pr, 8);
        pr += __shfl_xor(pr, 16);
        if (l == 0) {
            float total = ((float)(xe[0] + xe[1]) + __builtin_log2f(pr)) * LN2;
            out[b] = total - (xs[0] + xs[1]);
        }
    }
}

extern "C" void kernel_launch(void* const* d_in, const int* in_sizes, int n_in,
                              void* d_out, int out_size, void* d_ws, size_t ws_size,
                              hipStream_t stream) {
    const float* wtv   = (const float*)d_in[0];
    const float* trans = (const float*)d_in[1];
    const int*   rtag  = (const int*)d_in[2];
    (void)in_sizes; (void)n_in; (void)d_ws; (void)ws_size; (void)out_size;
    float* out = (float*)d_out;
    crf_kernel<<<512, 128, 0, stream>>>(wtv, trans, rtag, out);
}

// Round 4
// 155.747 us; speedup vs baseline: 1.0436x; 1.0436x over previous
//
#include <hip/hip_runtime.h>

// CRF loss on MI355X — R4: R2's LDS-broadcast recurrence, chain stripped bare.
// B=512, L=512, T=32, S=34. Output f32[512].
//
// One wave (64 thr) per batch. Lanes 0-31: forward linear-domain chain
// (alpha), lanes 32-63: backward chain (beta); meet at t=256:
// Z = sum_c alpha_256[c] * beta_256[c]. Inner loop per joint iteration:
// ds_write(1) -> wave_barrier -> ds_read_b128(8, broadcast) -> 32 fmac ->
// exact pow2 rescale (exponent of state[0], uniform VGPR -> no shuffles).
// Gold-path score computed in a separate fully-parallel pass (lane l covers
// timesteps 8l..8l+7), entirely off the recurrence chain.

#define F2  1.4426950408889634f   // log2(e)
#define LN2 0.6931471805599453f

__global__ __launch_bounds__(64) void crf_kernel(
    const float* __restrict__ wtv,    // [512,512,32]
    const float* __restrict__ trans,  // [34,34]
    const int*   __restrict__ rtag,   // [512,512]
    float* __restrict__ out)          // [512]
{
    __shared__ __align__(16) float tlds[1156];
    __shared__ __align__(16) float alds[64];   // [0..31] fwd alpha, [32..63] bwd g

    const int b = blockIdx.x;
    const int l = threadIdx.x;
    const int h = l >> 5;   // 0 = forward half, 1 = backward half
    const int c = l & 31;   // state-1 (states 1..32)

    const float* wb = wtv + (size_t)b * (512 * 32);
    const int*   tb = rtag + (size_t)b * 512;

    for (int k = l; k < 1156; k += 64) tlds[k] = trans[k];
    __syncthreads();

    // ---- gold-path score: parallel over timesteps, off the chain ----
    int tg[8];
    {
        const int4* tp = (const int4*)(tb + 8 * l);
        int4 q0 = tp[0], q1 = tp[1];
        tg[0] = q0.x; tg[1] = q0.y; tg[2] = q0.z; tg[3] = q0.w;
        tg[4] = q1.x; tg[5] = q1.y; tg[6] = q1.z; tg[7] = q1.w;
    }
    int tExtra = tb[(l < 63) ? (8 * l + 8) : 511];
    if (l == 63) tExtra = 33;                       // end term trans[tag_511][STOP]
    float path = 0.0f;
    #pragma unroll
    for (int j = 0; j < 8; ++j)                     // gold emissions
        path += wb[(8 * l + j) * 32 + (tg[j] - 1)];
    #pragma unroll
    for (int j = 0; j < 8; ++j) {                   // gold transitions
        int nxt = (j < 7) ? tg[j + 1] : tExtra;
        path += tlds[tg[j] * 34 + nxt];
    }
    if (l == 0) path += tlds[tg[0]];                // start term trans[0][tag_0]

    // ---- recurrence setup ----
    // T-operand: fwd tc[p] = expT[p+1][c+1] ; bwd tc[p] = expT[c+1][p+1]
    float tc[32];
    #pragma unroll
    for (int p = 0; p < 32; ++p) {
        float tv = h ? tlds[(c + 1) * 34 + (p + 1)]
                     : tlds[(p + 1) * 34 + (c + 1)];
        tc[p] = __builtin_exp2f(F2 * tv);
    }
    float seed = h ? 0.0f : __builtin_exp2f(F2 * tlds[c + 1]);  // expT[0][c+1] @ i==1

    // init: fwd st = alpha_0[c] = exp(obs0[c]) ; bwd st = beta_511 = 1
    float st = h ? 1.0f : __builtin_exp2f(F2 * wb[c]);

    // emission prefetch: iteration i uses row i (fwd) / row 512-i (bwd)
    const int rowstride = h ? -32 : 32;
    float vn[8];
    {
        const float* p0 = wb + (h ? 511 * 32 : 32) + c;   // rows for i=1..8
        #pragma unroll
        for (int j = 0; j < 8; ++j) vn[j] = p0[j * rowstride];
    }

    int   scaleE = 0;
    float bKeep  = 0.0f;
    int   bScale = 0;

    for (int t0 = 1; t0 <= 249; t0 += 8) {   // 32 blocks, i = t0..t0+7
        float eo[8];
        #pragma unroll
        for (int j = 0; j < 8; ++j) eo[j] = __builtin_exp2f(F2 * vn[j]);
        {   // prefetch next block's emissions (rows always in-bounds)
            const float* p0 = wb + (h ? (504 - t0) : (t0 + 8)) * 32 + c;
            #pragma unroll
            for (int j = 0; j < 8; ++j) vn[j] = p0[j * rowstride];
        }

        #pragma unroll
        for (int j = 0; j < 8; ++j) {
            // publish: fwd alpha, bwd g = beta*eo(current row)
            float wval = h ? st * eo[j] : st;
            alds[l] = wval;
            __builtin_amdgcn_wave_barrier();
            const float4* a4 = (const float4*)(alds + (h << 5));
            float4 x0 = a4[0], x1 = a4[1], x2 = a4[2], x3 = a4[3];
            float4 x4 = a4[4], x5 = a4[5], x6 = a4[6], x7 = a4[7];
            __builtin_amdgcn_wave_barrier();
            // uniform (per half-wave) rescale exponent from state[0]
            int k = ((__float_as_int(x0.x) >> 23) & 0xff) - 127;
            float a0 = x0.x * tc[0],  a1 = x0.y * tc[1];
            float a2 = x0.z * tc[2],  a3 = x0.w * tc[3];
            a0 = fmaf(x1.x, tc[4],  a0); a1 = fmaf(x1.y, tc[5],  a1);
            a2 = fmaf(x1.z, tc[6],  a2); a3 = fmaf(x1.w, tc[7],  a3);
            a0 = fmaf(x2.x, tc[8],  a0); a1 = fmaf(x2.y, tc[9],  a1);
            a2 = fmaf(x2.z, tc[10], a2); a3 = fmaf(x2.w, tc[11], a3);
            a0 = fmaf(x3.x, tc[12], a0); a1 = fmaf(x3.y, tc[13], a1);
            a2 = fmaf(x3.z, tc[14], a2); a3 = fmaf(x3.w, tc[15], a3);
            a0 = fmaf(x4.x, tc[16], a0); a1 = fmaf(x4.y, tc[17], a1);
            a2 = fmaf(x4.z, tc[18], a2); a3 = fmaf(x4.w, tc[19], a3);
            a0 = fmaf(x5.x, tc[20], a0); a1 = fmaf(x5.y, tc[21], a1);
            a2 = fmaf(x5.z, tc[22], a2); a3 = fmaf(x5.w, tc[23], a3);
            a0 = fmaf(x6.x, tc[24], a0); a1 = fmaf(x6.y, tc[25], a1);
            a2 = fmaf(x6.z, tc[26], a2); a3 = fmaf(x6.w, tc[27], a3);
            a0 = fmaf(x7.x, tc[28], a0); a1 = fmaf(x7.y, tc[29], a1);
            a2 = fmaf(x7.z, tc[30], a2); a3 = fmaf(x7.w, tc[31], a3);
            float s = (a0 + a1) + (a2 + a3);
            if (t0 == 1 && j == 0) s += seed;          // START path, i==1 only
            float res = s * __int_as_float((127 - k) << 23);  // exact pow2 rescale
            st = h ? res : res * eo[j];                // fwd folds eo post-matvec
            scaleE += k;
            if (t0 == 249 && j == 6) { bKeep = st; bScale = scaleE; }  // beta_256
        }
    }
    // (bwd's i==256 step computed garbage past bKeep; ignored)

    // ---- epilogue: Z = sum_c alpha_256[c] * beta_256[c] ----
    float bo   = __shfl_xor(bKeep, 32);     // fwd lanes receive beta_256[c]
    float prod = st * bo;                   // meaningful on lanes 0..31
    prod += __shfl_xor(prod, 1);
    prod += __shfl_xor(prod, 2);
    prod += __shfl_xor(prod, 4);
    prod += __shfl_xor(prod, 8);
    prod += __shfl_xor(prod, 16);
    int scB = __shfl_xor(bScale, 32);
    int scT = scaleE + scB;                 // valid on fwd lanes

    path += __shfl_xor(path, 1);
    path += __shfl_xor(path, 2);
    path += __shfl_xor(path, 4);
    path += __shfl_xor(path, 8);
    path += __shfl_xor(path, 16);
    path += __shfl_xor(path, 32);

    if (l == 0)
        out[b] = ((float)scT + __builtin_log2f(prod)) * LN2 - path;
}

extern "C" void kernel_launch(void* const* d_in, const int* in_sizes, int n_in,
                              void* d_out, int out_size, void* d_ws, size_t ws_size,
                              hipStream_t stream) {
    const float* wtv   = (const float*)d_in[0];
    const float* trans = (const float*)d_in[1];
    const int*   rtag  = (const int*)d_in[2];
    (void)in_sizes; (void)n_in; (void)d_ws; (void)ws_size; (void)out_size;
    float* out = (float*)d_out;
    crf_kernel<<<512, 64, 0, stream>>>(wtv, trans, rtag, out);
}

// Round 5
// 151.105 us; speedup vs baseline: 1.0757x; 1.0307x over previous
//
#include <hip/hip_runtime.h>

// CRF loss on MI355X — R5: R4's chain, two batches per wave, software-pipelined
// with one-iteration stagger so each batch's LDS round trip is covered by the
// other batch's compute blob. B=512, L=512, T=32, S=34. Output f32[512].
//
// Per wave (64 thr): batches bA=2*blk, bB=2*blk+1. Each batch: fwd chain on
// lanes 0-31 (alpha), bwd on lanes 32-63 (beta), meeting at t=256 (R4 logic).
// Phase p: pubA(p); readsA(p); computeB(p-1); pubB(p); readsB(p); computeA(p).
// Gold-path score: tag loads + emission gathers issued in prologue, summed in
// epilogue — zero work on the recurrence chain.

#define F2  1.4426950408889634f   // log2(e)
#define LN2 0.6931471805599453f

__device__ __forceinline__ void publish_read(float* alds, int l, int h,
                                             float wval, float4 (&x)[8]) {
    alds[l] = wval;
    __builtin_amdgcn_wave_barrier();
    const float4* a4 = (const float4*)(alds + (h << 5));
    #pragma unroll
    for (int k = 0; k < 8; ++k) x[k] = a4[k];
    __builtin_amdgcn_wave_barrier();
}

__device__ __forceinline__ float dot32(const float4 (&x)[8], const float (&tc)[32],
                                       int& kout) {
    kout = ((__float_as_int(x[0].x) >> 23) & 0xff) - 127;
    float a0 = x[0].x * tc[0], a1 = x[0].y * tc[1];
    float a2 = x[0].z * tc[2], a3 = x[0].w * tc[3];
    #pragma unroll
    for (int m = 1; m < 8; ++m) {
        a0 = fmaf(x[m].x, tc[4 * m + 0], a0);
        a1 = fmaf(x[m].y, tc[4 * m + 1], a1);
        a2 = fmaf(x[m].z, tc[4 * m + 2], a2);
        a3 = fmaf(x[m].w, tc[4 * m + 3], a3);
    }
    return (a0 + a1) + (a2 + a3);
}

__global__ __launch_bounds__(64) void crf_kernel(
    const float* __restrict__ wtv,    // [512,512,32]
    const float* __restrict__ trans,  // [34,34]
    const int*   __restrict__ rtag,   // [512,512]
    float* __restrict__ out)          // [512]
{
    __shared__ __align__(16) float tlds[1156];
    __shared__ __align__(16) float aldsA[64];
    __shared__ __align__(16) float aldsB[64];

    const int bA = blockIdx.x * 2, bB = bA + 1;
    const int l = threadIdx.x;
    const int h = l >> 5;   // 0 = fwd half, 1 = bwd half
    const int c = l & 31;

    const float* wA = wtv + (size_t)bA * 16384;
    const float* wB = wtv + (size_t)bB * 16384;
    const int*   tA = rtag + (size_t)bA * 512;
    const int*   tB = rtag + (size_t)bB * 512;

    // ---- prologue: gold-path tag loads + emission gathers (off-chain) ----
    int tgA[8], tgB[8];
    {
        const int4* p = (const int4*)(tA + 8 * l);
        int4 q0 = p[0], q1 = p[1];
        tgA[0]=q0.x; tgA[1]=q0.y; tgA[2]=q0.z; tgA[3]=q0.w;
        tgA[4]=q1.x; tgA[5]=q1.y; tgA[6]=q1.z; tgA[7]=q1.w;
    }
    {
        const int4* p = (const int4*)(tB + 8 * l);
        int4 q0 = p[0], q1 = p[1];
        tgB[0]=q0.x; tgB[1]=q0.y; tgB[2]=q0.z; tgB[3]=q0.w;
        tgB[4]=q1.x; tgB[5]=q1.y; tgB[6]=q1.z; tgB[7]=q1.w;
    }
    float geA[8], geB[8];   // gold emission gathers, consumed in epilogue
    #pragma unroll
    for (int j = 0; j < 8; ++j) geA[j] = wA[(8 * l + j) * 32 + (tgA[j] - 1)];
    #pragma unroll
    for (int j = 0; j < 8; ++j) geB[j] = wB[(8 * l + j) * 32 + (tgB[j] - 1)];

    for (int k = l; k < 1156; k += 64) tlds[k] = trans[k];
    __syncthreads();

    // gold-path transition sums (prologue; tags freed after this)
    int exA = __shfl_down(tgA[0], 1); if (l == 63) exA = 33;
    int exB = __shfl_down(tgB[0], 1); if (l == 63) exB = 33;
    float pathA = 0.0f, pathB = 0.0f;
    #pragma unroll
    for (int j = 0; j < 8; ++j) {
        int nA = (j < 7) ? tgA[j + 1] : exA;
        int nB = (j < 7) ? tgB[j + 1] : exB;
        pathA += tlds[tgA[j] * 34 + nA];
        pathB += tlds[tgB[j] * 34 + nB];
    }
    if (l == 0) { pathA += tlds[tgA[0]]; pathB += tlds[tgB[0]]; }  // start terms

    // ---- recurrence setup ----
    float tc[32];   // shared by both units (depends only on trans, h, c)
    #pragma unroll
    for (int p = 0; p < 32; ++p) {
        float tv = h ? tlds[(c + 1) * 34 + (p + 1)]
                     : tlds[(p + 1) * 34 + (c + 1)];
        tc[p] = __builtin_exp2f(F2 * tv);
    }
    float seed = h ? 0.0f : __builtin_exp2f(F2 * tlds[c + 1]);  // expT[0][c+1] @ i==1

    float stA = h ? 1.0f : __builtin_exp2f(F2 * wA[c]);
    float stB = h ? 1.0f : __builtin_exp2f(F2 * wB[c]);

    const int rs = h ? -32 : 32;
    float vnA[8], vnB[8];
    {
        const float* p0 = wA + (h ? 511 * 32 : 32) + c;   // rows for i=1..8
        #pragma unroll
        for (int j = 0; j < 8; ++j) vnA[j] = p0[j * rs];
    }
    {
        const float* p0 = wB + (h ? 511 * 32 : 32) + c;
        #pragma unroll
        for (int j = 0; j < 8; ++j) vnB[j] = p0[j * rs];
    }

    float eoA[8];    // unit A: eo for iteration t0+j at index j
    float eoB9[9];   // unit B: [0] = prev block's last; [1+j] = iteration t0+j
    eoB9[8] = 0.0f;  // never used before first refresh

    int   scaleA = 0, scaleB = 0;
    float bKeepA = 0.0f, bKeepB = 0.0f;
    int   bScaleA = 0, bScaleB = 0;
    float4 xA[8], xB[8];

    for (int t0 = 1; t0 <= 249; t0 += 8) {
        #pragma unroll
        for (int j = 0; j < 8; ++j) eoA[j] = __builtin_exp2f(F2 * vnA[j]);
        eoB9[0] = eoB9[8];
        #pragma unroll
        for (int j = 0; j < 8; ++j) eoB9[1 + j] = __builtin_exp2f(F2 * vnB[j]);
        {   // prefetch next block's emissions (rows always in-bounds)
            const float* pa = wA + (h ? (504 - t0) : (t0 + 8)) * 32 + c;
            const float* pb = wB + (h ? (504 - t0) : (t0 + 8)) * 32 + c;
            #pragma unroll
            for (int j = 0; j < 8; ++j) { vnA[j] = pa[j * rs]; vnB[j] = pb[j * rs]; }
        }

        #pragma unroll
        for (int j = 0; j < 8; ++j) {
            // ---- pub + reads A (iteration p = t0+j) ----
            publish_read(aldsA, l, h, h ? stA * eoA[j] : stA, xA);

            // ---- compute B (iteration p-1); skipped at p==1 ----
            if (!(t0 == 1 && j == 0)) {
                int kB; float s = dot32(xB, tc, kB);
                if (t0 == 1 && j == 1) s += seed;          // B's iteration 1
                float res = s * __int_as_float((127 - kB) << 23);
                stB = h ? res : res * eoB9[j];
                scaleB += kB;
                if (t0 == 249 && j == 7) { bKeepB = stB; bScaleB = scaleB; }
            }

            // ---- pub + reads B (iteration p) ----
            publish_read(aldsB, l, h, h ? stB * eoB9[j + 1] : stB, xB);

            // ---- compute A (iteration p) ----
            {
                int kA; float s = dot32(xA, tc, kA);
                if (t0 == 1 && j == 0) s += seed;          // A's iteration 1
                float res = s * __int_as_float((127 - kA) << 23);
                stA = h ? res : res * eoA[j];
                scaleA += kA;
                if (t0 == 249 && j == 6) { bKeepA = stA; bScaleA = scaleA; }
            }
        }
    }
    // phase 257: compute B (iteration 256)
    {
        int kB; float s = dot32(xB, tc, kB);
        float res = s * __int_as_float((127 - kB) << 23);
        stB = h ? res : res * eoB9[8];
        scaleB += kB;
    }

    // ---- epilogue ----
    float boA = __shfl_xor(bKeepA, 32);
    float boB = __shfl_xor(bKeepB, 32);
    float prA = stA * boA, prB = stB * boB;   // meaningful on lanes 0..31
    #pragma unroll
    for (int d = 1; d <= 16; d <<= 1) {
        prA += __shfl_xor(prA, d);
        prB += __shfl_xor(prB, d);
    }
    int scA = scaleA + __shfl_xor(bScaleA, 32);
    int scB = scaleB + __shfl_xor(bScaleB, 32);

    float sumA = pathA, sumB = pathB;
    #pragma unroll
    for (int j = 0; j < 8; ++j) { sumA += geA[j]; sumB += geB[j]; }
    #pragma unroll
    for (int d = 1; d <= 32; d <<= 1) {
        sumA += __shfl_xor(sumA, d);
        sumB += __shfl_xor(sumB, d);
    }

    if (l == 0) {
        out[bA] = ((float)scA + __builtin_log2f(prA)) * LN2 - sumA;
        out[bB] = ((float)scB + __builtin_log2f(prB)) * LN2 - sumB;
    }
}

extern "C" void kernel_launch(void* const* d_in, const int* in_sizes, int n_in,
                              void* d_out, int out_size, void* d_ws, size_t ws_size,
                              hipStream_t stream) {
    const float* wtv   = (const float*)d_in[0];
    const float* trans = (const float*)d_in[1];
    const int*   rtag  = (const int*)d_in[2];
    (void)in_sizes; (void)n_in; (void)d_ws; (void)ws_size; (void)out_size;
    float* out = (float*)d_out;
    crf_kernel<<<256, 64, 0, stream>>>(wtv, trans, rtag, out);
}